// Round 3
// baseline (1071.360 us; speedup 1.0000x reference)
//
#include <hip/hip_runtime.h>

typedef _Float16 f16;
typedef _Float16 f16x2 __attribute__((ext_vector_type(2)));
typedef _Float16 f16x8 __attribute__((ext_vector_type(8)));
typedef float f32x4 __attribute__((ext_vector_type(4)));

namespace {

constexpr int kC = 16, kN = 8192, kH = 181, kOut = 3;
constexpr int kMB = 64;            // rows per block
constexpr int kKpad = 384;         // 12 ksteps * 32
constexpr int kNT = 48;            // n-tiles of 16 cols (Npad = 768)
constexpr int kKS = 12;            // k-steps of 32
constexpr int kRowB = kKpad * 2;   // 768 bytes per LDS activation row
constexpr float kOmega = 30.f, kS2 = 100.f;

constexpr size_t kWLayerStride = (size_t)kNT * kKS * 64 * 8;  // f16 elems per (c,layer)
constexpr size_t kWfOff = kWLayerStride * kC * 2;             // f16 elems
constexpr size_t kWfStride = (size_t)kKS * 64 * 8;

// XOR-swizzled LDS address (row stride 768B -> bank-degenerate without it).
__device__ __forceinline__ int swz(int row, int colb) {
  return row * kRowB + (colb ^ ((row & 7) << 4));
}

// 4x4 transpose across the 4-lane comp group (lane bits 0..1).
// In: v_j = C[row_off j][comp = lane&3]. Out: v_j = C[row_off = lane&3][comp j].
__device__ __forceinline__ void xpose4(float& v0, float& v1, float& v2, float& v3, int lane) {
  const bool b0 = lane & 1, b1 = lane & 2;
  float x0 = b0 ? v0 : v1;
  float x1 = b0 ? v2 : v3;
  x0 = __shfl_xor(x0, 1, 64);
  x1 = __shfl_xor(x1, 1, 64);
  if (b0) { v0 = x0; v2 = x1; } else { v1 = x0; v3 = x1; }
  float y0 = b1 ? v0 : v2;
  float y1 = b1 ? v1 : v3;
  y0 = __shfl_xor(y0, 2, 64);
  y1 = __shfl_xor(y1, 2, 64);
  if (b1) { v0 = y0; v1 = y1; } else { v2 = y0; v3 = y1; }
}

// ---- prep: pack hidden-layer complex weights into fp16 B-fragment order
// ws[c][L][nt][ks][lane][8]; K rows 2i/2i+1 = (x_re,x_im), N cols 4o+comp.
__global__ __launch_bounds__(768) void prep_hidden(
    const int* __restrict__ model_idx,
    const float* __restrict__ W1a, const float* __restrict__ W1b,
    const float* __restrict__ W2a, const float* __restrict__ W2b,
    f16* __restrict__ ws)
{
  __shared__ float s[kH][2][4][2];   // [i][branch][o_sub][reim]
  const int bid = blockIdx.x;
  const int c  = bid / (2 * kNT);
  const int L  = (bid / kNT) % 2;
  const int nt = bid % kNT;
  const int m  = model_idx[c];
  const float* Wa = (L == 0 ? W1a : W2a) + (size_t)m * kH * kH * 2;
  const float* Wb = (L == 0 ? W1b : W2b) + (size_t)m * kH * kH * 2;
  const int t = threadIdx.x;
  if (t < 2 * kH) {
    const int i = t >> 1, br = t & 1;
    const float* src = (br ? Wb : Wa) + ((size_t)i * kH + nt * 4) * 2;
#pragma unroll
    for (int e = 0; e < 8; ++e) {
      const int osub = e >> 1, reim = e & 1;
      s[i][br][osub][reim] = (nt * 4 + osub < kH) ? src[osub * 2 + reim] : 0.f;
    }
  }
  __syncthreads();
  const int ks = t >> 6, lane = t & 63;
  const int kg = lane >> 4, l15 = lane & 15;
  const int osub = l15 >> 2, comp = l15 & 3, br = comp >> 1;
  const int o = nt * 4 + osub;
  f16x8 v;
#pragma unroll
  for (int j = 0; j < 8; ++j) {
    const int k = ks * 32 + kg * 8 + j;
    float f = 0.f;
    if (k < 2 * kH && o < kH) {
      const int i = k >> 1, kodd = k & 1;
      const int reim = kodd ? (1 - (comp & 1)) : (comp & 1);
      f = s[i][br][osub][reim];
      if (kodd && !(comp & 1)) f = -f;   // -w_im for real-output cols
    }
    v[j] = (f16)f;
  }
  *(f16x8*)&ws[(((size_t)(c * 2 + L) * kNT + nt) * kKS + ks) * 512 + lane * 8] = v;
}

// ---- prep: final layer (real part): col j<3, k=2i -> wf_re, 2i+1 -> -wf_im
__global__ __launch_bounds__(768) void prep_final(
    const int* __restrict__ model_idx, const float* __restrict__ Wf,
    f16* __restrict__ ws)
{
  const int c = blockIdx.x;
  const int m = model_idx[c];
  const int t = threadIdx.x;
  const int ks = t >> 6, lane = t & 63;
  const int kg = lane >> 4, col = lane & 15;
  f16x8 v;
#pragma unroll
  for (int j = 0; j < 8; ++j) {
    const int k = ks * 32 + kg * 8 + j;
    float f = 0.f;
    if (k < 2 * kH && col < kOut) {
      const int i = k >> 1;
      const float* p = &Wf[(((size_t)m * kH + i) * kOut + col) * 2];
      f = (k & 1) ? -p[1] : p[0];
    }
    v[j] = (f16)f;
  }
  *(f16x8*)&ws[kWfOff + ((size_t)c * kKS + ks) * 512 + lane * 8] = v;
}

// ---- one hidden layer, IN PLACE: GEMM reads all of X, outputs held in regs,
// then barrier -> overwrite X -> barrier. Wave tile 64x192 (4 g-groups of 3 nt).
__device__ __forceinline__ void hidden_gemm_inplace(
    char* __restrict__ X, const f16x8* __restrict__ wl,
    const float* __restrict__ ba, const float* __restrict__ bb,
    int w, int lane)
{
  const int kg = lane >> 4, l15 = lane & 15;
  const int comp = l15 & 3, osub = l15 >> 2;
  f16x2 held[4][4][3];   // [g][mt][tn]

#pragma unroll
  for (int g = 0; g < 4; ++g) {
    const int nt0 = w * 12 + g * 3;
    f32x4 acc[4][3];
#pragma unroll
    for (int tn = 0; tn < 3; ++tn) {
      const int q = (nt0 + tn) * 4 + osub;
      float bv = 0.f;
      if (q < kH) bv = ((comp & 2) ? bb : ba)[q * 2 + (comp & 1)];
#pragma unroll
      for (int mt = 0; mt < 4; ++mt) acc[mt][tn] = {bv, bv, bv, bv};
    }
    f16x8 bC[3], bN[3];
#pragma unroll
    for (int tn = 0; tn < 3; ++tn) bC[tn] = wl[((size_t)(nt0 + tn) * kKS) * 64 + lane];
#pragma unroll
    for (int ks = 0; ks < kKS; ++ks) {
      if (ks + 1 < kKS) {   // prefetch next k-step of B (global/L2)
#pragma unroll
        for (int tn = 0; tn < 3; ++tn)
          bN[tn] = wl[((size_t)(nt0 + tn) * kKS + ks + 1) * 64 + lane];
      }
#pragma unroll
      for (int mt = 0; mt < 4; ++mt) {
        const f16x8 a = *(const f16x8*)(X + swz(l15 + 16 * mt, ks * 64 + kg * 16));
#pragma unroll
        for (int tn = 0; tn < 3; ++tn)
          acc[mt][tn] = __builtin_amdgcn_mfma_f32_16x16x32_f16(a, bC[tn], acc[mt][tn], 0, 0, 0);
      }
      if (ks + 1 < kKS) {
#pragma unroll
        for (int tn = 0; tn < 3; ++tn) bC[tn] = bN[tn];
      }
    }
    // Gabor activation, distributed: transpose 4x4 (j x comp) within the
    // comp-group so EVERY lane computes exactly one (row, neuron) activation.
#pragma unroll
    for (int mt = 0; mt < 4; ++mt)
#pragma unroll
      for (int tn = 0; tn < 3; ++tn) {
        float v0 = acc[mt][tn][0], v1 = acc[mt][tn][1];
        float v2 = acc[mt][tn][2], v3 = acc[mt][tn][3];
        xpose4(v0, v1, v2, v3, lane);
        // v0..v3 = (la_re, la_im, lb_re, lb_im) at row_off = comp
        const float mag = kS2 * (v0 * v0 + v1 * v1 + v2 * v2 + v3 * v3);
        const float amp = __expf(fmaf(-kOmega, v1, -mag));
        const float ph  = kOmega * v0;
        held[g][mt][tn] = {(f16)(amp * __cosf(ph)), (f16)(amp * __sinf(ph))};
      }
  }

  __syncthreads();   // all waves done READING X
#pragma unroll
  for (int g = 0; g < 4; ++g)
#pragma unroll
    for (int mt = 0; mt < 4; ++mt)
#pragma unroll
      for (int tn = 0; tn < 3; ++tn) {
        const int row = mt * 16 + kg * 4 + comp;
        const int q   = (w * 12 + g * 3 + tn) * 4 + osub;
        *(f16x2*)(X + swz(row, q * 4)) = held[g][mt][tn];
      }
  __syncthreads();   // X fully rewritten
}

__global__ __launch_bounds__(256, 3) void wire_main(
    const float* __restrict__ inp, const int* __restrict__ indices,
    const int* __restrict__ model_idx, const int* __restrict__ bias_idx,
    const float* __restrict__ W0a, const float* __restrict__ b0a,
    const float* __restrict__ W0b, const float* __restrict__ b0b,
    const float* __restrict__ b1a, const float* __restrict__ b1b,
    const float* __restrict__ b2a, const float* __restrict__ b2b,
    const float* __restrict__ bf, const f16* __restrict__ wsW,
    float* __restrict__ out)
{
  __shared__ __align__(16) char X[kMB * kRowB];   // single 48 KB buffer
  const int d = blockIdx.x;
  const int lg = (d & 7) * 256 + (d >> 3);   // XCD swizzle (2048 % 8 == 0)
  const int c = lg >> 7;
  const int n0 = (lg & 127) * kMB;
  const int src = indices[c], m = model_idx[c], bix = bias_idx[c];
  const int tid = threadIdx.x, w = tid >> 6, lane = tid & 63;

  // ---- layer 0 (VALU, f32): real 2->181 + activation, write X fp16
  {
    const int r = tid >> 2, sub = tid & 3;
    const float2 xv = *(const float2*)&inp[((size_t)src * kN + n0 + r) * 2];
    const float* w0a0 = W0a + (size_t)(m * 2 + 0) * kH;
    const float* w0a1 = W0a + (size_t)(m * 2 + 1) * kH;
    const float* w0b0 = W0b + (size_t)(m * 2 + 0) * kH;
    const float* w0b1 = W0b + (size_t)(m * 2 + 1) * kH;
    const float* b0av = b0a + (size_t)bix * kH;
    const float* b0bv = b0b + (size_t)bix * kH;
    for (int t = 0; t < 48; ++t) {
      const int o = sub + 4 * t;
      float la = 0.f, lb = 0.f;
      if (o < kH) {
        la = fmaf(xv.y, w0a1[o], fmaf(xv.x, w0a0[o], b0av[o]));
        lb = fmaf(xv.y, w0b1[o], fmaf(xv.x, w0b0[o], b0bv[o]));
      }
      const float amp = __expf(-kS2 * fmaf(la, la, lb * lb));
      const float ph = kOmega * la;
      f16x2 pv = {(f16)(amp * __cosf(ph)), (f16)(amp * __sinf(ph))};
      *(f16x2*)(&X[0] + swz(r, o * 4)) = pv;
    }
  }
  __syncthreads();
  hidden_gemm_inplace(X, (const f16x8*)(wsW + (size_t)(c * 2 + 0) * kWLayerStride),
                      b1a + (size_t)bix * kH * 2, b1b + (size_t)bix * kH * 2, w, lane);
  hidden_gemm_inplace(X, (const f16x8*)(wsW + (size_t)(c * 2 + 1) * kWLayerStride),
                      b2a + (size_t)bix * kH * 2, b2b + (size_t)bix * kH * 2, w, lane);
  // ---- final complex 181->3, real part (wave w = row-tile w)
  {
    const int kg = lane >> 4, l15 = lane & 15;
    const f16x8* wf = (const f16x8*)(wsW + kWfOff + (size_t)c * kWfStride);
    f32x4 facc = {0.f, 0.f, 0.f, 0.f};
#pragma unroll
    for (int ks = 0; ks < kKS; ++ks) {
      f16x8 a = *(const f16x8*)(&X[0] + swz(l15 + 16 * w, ks * 64 + kg * 16));
      f16x8 b = wf[(size_t)ks * 64 + lane];
      facc = __builtin_amdgcn_mfma_f32_16x16x32_f16(a, b, facc, 0, 0, 0);
    }
    if (l15 < kOut) {
      const float bfr = bf[(bix * kOut + l15) * 2];
#pragma unroll
      for (int j = 0; j < 4; ++j) {
        const int row = w * 16 + kg * 4 + j;
        out[((size_t)c * kN + n0 + row) * kOut + l15] = facc[j] + bfr;
      }
    }
  }
}

}  // namespace

extern "C" void kernel_launch(void* const* d_in, const int* in_sizes, int n_in,
                              void* d_out, int out_size, void* d_ws, size_t ws_size,
                              hipStream_t stream) {
  const float* inp       = (const float*)d_in[0];
  const int*   indices   = (const int*)  d_in[1];
  const int*   model_idx = (const int*)  d_in[2];
  const int*   bias_idx  = (const int*)  d_in[3];
  const float* W0a = (const float*)d_in[4];
  const float* b0a = (const float*)d_in[5];
  const float* W0b = (const float*)d_in[6];
  const float* b0b = (const float*)d_in[7];
  const float* W1a = (const float*)d_in[8];
  const float* b1a = (const float*)d_in[9];
  const float* W1b = (const float*)d_in[10];
  const float* b1b = (const float*)d_in[11];
  const float* W2a = (const float*)d_in[12];
  const float* b2a = (const float*)d_in[13];
  const float* W2b = (const float*)d_in[14];
  const float* b2b = (const float*)d_in[15];
  const float* Wf  = (const float*)d_in[16];
  const float* bff = (const float*)d_in[17];
  f16*   ws  = (f16*)d_ws;     // needs ~19.1 MB
  float* out = (float*)d_out;

  prep_hidden<<<dim3(kC * 2 * kNT), dim3(768), 0, stream>>>(model_idx, W1a, W1b, W2a, W2b, ws);
  prep_final<<<dim3(kC), dim3(768), 0, stream>>>(model_idx, Wf, ws);
  wire_main<<<dim3(kC * (kN / kMB)), dim3(256), 0, stream>>>(
      inp, indices, model_idx, bias_idx, W0a, b0a, W0b, b0b,
      b1a, b1b, b2a, b2b, bff, ws, out);
}

// Round 4
// 400.926 us; speedup vs baseline: 2.6722x; 2.6722x over previous
//
#include <hip/hip_runtime.h>

typedef _Float16 f16;
typedef _Float16 f16x2 __attribute__((ext_vector_type(2)));
typedef _Float16 f16x8 __attribute__((ext_vector_type(8)));
typedef float f32x4 __attribute__((ext_vector_type(4)));

namespace {

constexpr int kC = 16, kN = 8192, kH = 181, kOut = 3;
constexpr int kMB = 32;            // rows per block (ping-pong, no held regs)
constexpr int kKpad = 384;         // 12 ksteps * 32
constexpr int kNT = 48;            // n-tiles of 16 cols (Npad = 768)
constexpr int kKS = 12;            // k-steps of 32
constexpr int kRowB = kKpad * 2;   // 768 bytes per LDS activation row
constexpr float kOmega = 30.f, kS2 = 100.f;

constexpr size_t kWLayerStride = (size_t)kNT * kKS * 64 * 8;  // f16 elems per (c,layer)
constexpr size_t kWfOff = kWLayerStride * kC * 2;             // f16 elems
constexpr size_t kWfStride = (size_t)kKS * 64 * 8;

// XOR-swizzled LDS address (row stride 768B -> bank-degenerate without it).
__device__ __forceinline__ int swz(int row, int colb) {
  return row * kRowB + (colb ^ ((row & 7) << 4));
}

// 4x4 transpose across the 4-lane comp group (lane bits 0..1).
// In: v_j = C[row_off j][comp = lane&3]. Out: v_j = C[row_off = lane&3][comp j].
__device__ __forceinline__ void xpose4(float& v0, float& v1, float& v2, float& v3, int lane) {
  const bool b0 = lane & 1, b1 = lane & 2;
  float x0 = b0 ? v0 : v1;
  float x1 = b0 ? v2 : v3;
  x0 = __shfl_xor(x0, 1, 64);
  x1 = __shfl_xor(x1, 1, 64);
  if (b0) { v0 = x0; v2 = x1; } else { v1 = x0; v3 = x1; }
  float y0 = b1 ? v0 : v2;
  float y1 = b1 ? v1 : v3;
  y0 = __shfl_xor(y0, 2, 64);
  y1 = __shfl_xor(y1, 2, 64);
  if (b1) { v0 = y0; v1 = y1; } else { v2 = y0; v3 = y1; }
}

// ---- prep: pack hidden-layer complex weights into fp16 B-fragment order
// ws[c][L][nt][ks][lane][8]; K rows 2i/2i+1 = (x_re,x_im), N cols 4o+comp.
__global__ __launch_bounds__(768) void prep_hidden(
    const int* __restrict__ model_idx,
    const float* __restrict__ W1a, const float* __restrict__ W1b,
    const float* __restrict__ W2a, const float* __restrict__ W2b,
    f16* __restrict__ ws)
{
  __shared__ float s[kH][2][4][2];   // [i][branch][o_sub][reim]
  const int bid = blockIdx.x;
  const int c  = bid / (2 * kNT);
  const int L  = (bid / kNT) % 2;
  const int nt = bid % kNT;
  const int m  = model_idx[c];
  const float* Wa = (L == 0 ? W1a : W2a) + (size_t)m * kH * kH * 2;
  const float* Wb = (L == 0 ? W1b : W2b) + (size_t)m * kH * kH * 2;
  const int t = threadIdx.x;
  if (t < 2 * kH) {
    const int i = t >> 1, br = t & 1;
    const float* src = (br ? Wb : Wa) + ((size_t)i * kH + nt * 4) * 2;
#pragma unroll
    for (int e = 0; e < 8; ++e) {
      const int osub = e >> 1, reim = e & 1;
      s[i][br][osub][reim] = (nt * 4 + osub < kH) ? src[osub * 2 + reim] : 0.f;
    }
  }
  __syncthreads();
  const int ks = t >> 6, lane = t & 63;
  const int kg = lane >> 4, l15 = lane & 15;
  const int osub = l15 >> 2, comp = l15 & 3, br = comp >> 1;
  const int o = nt * 4 + osub;
  f16x8 v;
#pragma unroll
  for (int j = 0; j < 8; ++j) {
    const int k = ks * 32 + kg * 8 + j;
    float f = 0.f;
    if (k < 2 * kH && o < kH) {
      const int i = k >> 1, kodd = k & 1;
      const int reim = kodd ? (1 - (comp & 1)) : (comp & 1);
      f = s[i][br][osub][reim];
      if (kodd && !(comp & 1)) f = -f;   // -w_im for real-output cols
    }
    v[j] = (f16)f;
  }
  *(f16x8*)&ws[(((size_t)(c * 2 + L) * kNT + nt) * kKS + ks) * 512 + lane * 8] = v;
}

// ---- prep: final layer (real part): col j<3, k=2i -> wf_re, 2i+1 -> -wf_im
__global__ __launch_bounds__(768) void prep_final(
    const int* __restrict__ model_idx, const float* __restrict__ Wf,
    f16* __restrict__ ws)
{
  const int c = blockIdx.x;
  const int m = model_idx[c];
  const int t = threadIdx.x;
  const int ks = t >> 6, lane = t & 63;
  const int kg = lane >> 4, col = lane & 15;
  f16x8 v;
#pragma unroll
  for (int j = 0; j < 8; ++j) {
    const int k = ks * 32 + kg * 8 + j;
    float f = 0.f;
    if (k < 2 * kH && col < kOut) {
      const int i = k >> 1;
      const float* p = &Wf[(((size_t)m * kH + i) * kOut + col) * 2];
      f = (k & 1) ? -p[1] : p[0];
    }
    v[j] = (f16)f;
  }
  *(f16x8*)&ws[kWfOff + ((size_t)c * kKS + ks) * 512 + lane * 8] = v;
}

// ---- one hidden layer: GEMM (32 rows x 768 cols, K=384) + distributed Gabor
// activation, src buffer -> dst buffer (no intra-layer barrier needed).
__device__ __forceinline__ void hidden_gemm(
    const char* __restrict__ Xs, char* __restrict__ Xd,
    const f16x8* __restrict__ wl,
    const float* __restrict__ ba, const float* __restrict__ bb,
    int w, int lane)
{
  const int kg = lane >> 4, l15 = lane & 15;
  const int comp = l15 & 3, osub = l15 >> 2;
#pragma unroll
  for (int g = 0; g < 4; ++g) {
    const int nt0 = w * 12 + g * 3;
    f32x4 acc[2][3];
#pragma unroll
    for (int tn = 0; tn < 3; ++tn) {
      const int q = (nt0 + tn) * 4 + osub;
      float bv = 0.f;
      if (q < kH) bv = ((comp & 2) ? bb : ba)[q * 2 + (comp & 1)];
#pragma unroll
      for (int mt = 0; mt < 2; ++mt) acc[mt][tn] = {bv, bv, bv, bv};
    }
    f16x8 aC[2], aN[2], bC[3], bN[3];
#pragma unroll
    for (int tn = 0; tn < 3; ++tn) bC[tn] = wl[((size_t)(nt0 + tn) * kKS) * 64 + lane];
#pragma unroll
    for (int mt = 0; mt < 2; ++mt)
      aC[mt] = *(const f16x8*)(Xs + swz(l15 + 16 * mt, kg * 16));
#pragma unroll
    for (int ks = 0; ks < kKS; ++ks) {
      if (ks + 1 < kKS) {   // prefetch next k-step (B from L2, A from LDS)
#pragma unroll
        for (int tn = 0; tn < 3; ++tn)
          bN[tn] = wl[((size_t)(nt0 + tn) * kKS + ks + 1) * 64 + lane];
#pragma unroll
        for (int mt = 0; mt < 2; ++mt)
          aN[mt] = *(const f16x8*)(Xs + swz(l15 + 16 * mt, (ks + 1) * 64 + kg * 16));
      }
#pragma unroll
      for (int mt = 0; mt < 2; ++mt)
#pragma unroll
        for (int tn = 0; tn < 3; ++tn)
          acc[mt][tn] = __builtin_amdgcn_mfma_f32_16x16x32_f16(aC[mt], bC[tn], acc[mt][tn], 0, 0, 0);
#pragma unroll
      for (int mt = 0; mt < 2; ++mt) aC[mt] = aN[mt];
#pragma unroll
      for (int tn = 0; tn < 3; ++tn) bC[tn] = bN[tn];
    }
    // Distributed activation: 4x4 transpose within comp-group, every lane
    // computes one (row, neuron) Gabor and writes f16x2 straight to Xd.
#pragma unroll
    for (int mt = 0; mt < 2; ++mt)
#pragma unroll
      for (int tn = 0; tn < 3; ++tn) {
        float v0 = acc[mt][tn][0], v1 = acc[mt][tn][1];
        float v2 = acc[mt][tn][2], v3 = acc[mt][tn][3];
        xpose4(v0, v1, v2, v3, lane);
        // v0..v3 = (la_re, la_im, lb_re, lb_im) at row_off = comp
        const float mag = kS2 * (v0 * v0 + v1 * v1 + v2 * v2 + v3 * v3);
        const float amp = __expf(fmaf(-kOmega, v1, -mag));
        const float ph  = kOmega * v0;
        f16x2 pv = {(f16)(amp * __cosf(ph)), (f16)(amp * __sinf(ph))};
        const int row = mt * 16 + kg * 4 + comp;
        const int q   = (nt0 + tn) * 4 + osub;
        *(f16x2*)(Xd + swz(row, q * 4)) = pv;
      }
  }
}

__global__ __launch_bounds__(256) __attribute__((amdgpu_waves_per_eu(3, 3)))
void wire_main(
    const float* __restrict__ inp, const int* __restrict__ indices,
    const int* __restrict__ model_idx, const int* __restrict__ bias_idx,
    const float* __restrict__ W0a, const float* __restrict__ b0a,
    const float* __restrict__ W0b, const float* __restrict__ b0b,
    const float* __restrict__ b1a, const float* __restrict__ b1b,
    const float* __restrict__ b2a, const float* __restrict__ b2b,
    const float* __restrict__ bf, const f16* __restrict__ wsW,
    float* __restrict__ out)
{
  __shared__ __align__(16) char X0[kMB * kRowB];   // 24 KB
  __shared__ __align__(16) char X1[kMB * kRowB];   // 24 KB
  const int d = blockIdx.x;
  const int lg = (d & 7) * 512 + (d >> 3);   // XCD swizzle (4096 % 8 == 0)
  const int c = lg >> 8;
  const int n0 = (lg & 255) * kMB;
  const int src = indices[c], m = model_idx[c], bix = bias_idx[c];
  const int tid = threadIdx.x, w = tid >> 6, lane = tid & 63;

  // ---- layer 0 (VALU, f32): real 2->181 + activation, write X0 fp16
  {
    const int r = tid >> 3, sub = tid & 7;
    const float2 xv = *(const float2*)&inp[((size_t)src * kN + n0 + r) * 2];
    const float* w0a0 = W0a + (size_t)(m * 2 + 0) * kH;
    const float* w0a1 = W0a + (size_t)(m * 2 + 1) * kH;
    const float* w0b0 = W0b + (size_t)(m * 2 + 0) * kH;
    const float* w0b1 = W0b + (size_t)(m * 2 + 1) * kH;
    const float* b0av = b0a + (size_t)bix * kH;
    const float* b0bv = b0b + (size_t)bix * kH;
    for (int t = 0; t < 24; ++t) {
      const int o = sub + 8 * t;
      float la = 0.f, lb = 0.f;
      if (o < kH) {
        la = fmaf(xv.y, w0a1[o], fmaf(xv.x, w0a0[o], b0av[o]));
        lb = fmaf(xv.y, w0b1[o], fmaf(xv.x, w0b0[o], b0bv[o]));
      }
      const float amp = __expf(-kS2 * fmaf(la, la, lb * lb));
      const float ph = kOmega * la;
      f16x2 pv = {(f16)(amp * __cosf(ph)), (f16)(amp * __sinf(ph))};
      *(f16x2*)(&X0[0] + swz(r, o * 4)) = pv;
    }
  }
  __syncthreads();
  hidden_gemm(X0, X1, (const f16x8*)(wsW + (size_t)(c * 2 + 0) * kWLayerStride),
              b1a + (size_t)bix * kH * 2, b1b + (size_t)bix * kH * 2, w, lane);
  __syncthreads();
  hidden_gemm(X1, X0, (const f16x8*)(wsW + (size_t)(c * 2 + 1) * kWLayerStride),
              b2a + (size_t)bix * kH * 2, b2b + (size_t)bix * kH * 2, w, lane);
  __syncthreads();
  // ---- final complex 181->3, real part; waves 0,1 own the two 16-row tiles
  if (w < 2) {
    const int kg = lane >> 4, l15 = lane & 15;
    const f16x8* wf = (const f16x8*)(wsW + kWfOff + (size_t)c * kWfStride);
    f32x4 facc = {0.f, 0.f, 0.f, 0.f};
#pragma unroll
    for (int ks = 0; ks < kKS; ++ks) {
      f16x8 a = *(const f16x8*)(&X0[0] + swz(l15 + 16 * w, ks * 64 + kg * 16));
      f16x8 b = wf[(size_t)ks * 64 + lane];
      facc = __builtin_amdgcn_mfma_f32_16x16x32_f16(a, b, facc, 0, 0, 0);
    }
    if (l15 < kOut) {
      const float bfr = bf[(bix * kOut + l15) * 2];
#pragma unroll
      for (int j = 0; j < 4; ++j) {
        const int row = w * 16 + kg * 4 + j;
        out[((size_t)c * kN + n0 + row) * kOut + l15] = facc[j] + bfr;
      }
    }
  }
}

}  // namespace

extern "C" void kernel_launch(void* const* d_in, const int* in_sizes, int n_in,
                              void* d_out, int out_size, void* d_ws, size_t ws_size,
                              hipStream_t stream) {
  const float* inp       = (const float*)d_in[0];
  const int*   indices   = (const int*)  d_in[1];
  const int*   model_idx = (const int*)  d_in[2];
  const int*   bias_idx  = (const int*)  d_in[3];
  const float* W0a = (const float*)d_in[4];
  const float* b0a = (const float*)d_in[5];
  const float* W0b = (const float*)d_in[6];
  const float* b0b = (const float*)d_in[7];
  const float* W1a = (const float*)d_in[8];
  const float* b1a = (const float*)d_in[9];
  const float* W1b = (const float*)d_in[10];
  const float* b1b = (const float*)d_in[11];
  const float* W2a = (const float*)d_in[12];
  const float* b2a = (const float*)d_in[13];
  const float* W2b = (const float*)d_in[14];
  const float* b2b = (const float*)d_in[15];
  const float* Wf  = (const float*)d_in[16];
  const float* bff = (const float*)d_in[17];
  f16*   ws  = (f16*)d_ws;     // needs ~19.1 MB
  float* out = (float*)d_out;

  prep_hidden<<<dim3(kC * 2 * kNT), dim3(768), 0, stream>>>(model_idx, W1a, W1b, W2a, W2b, ws);
  prep_final<<<dim3(kC), dim3(768), 0, stream>>>(model_idx, Wf, ws);
  wire_main<<<dim3(kC * (kN / kMB)), dim3(256), 0, stream>>>(
      inp, indices, model_idx, bias_idx, W0a, b0a, W0b, b0b,
      b1a, b1b, b2a, b2b, bff, ws, out);
}